// Round 2
// baseline (963.841 us; speedup 1.0000x reference)
//
#include <hip/hip_runtime.h>

#define NN 100000
#define NE 1600000
#define FDIM 128
#define NACT 8
#define NG 1024

// ---------------------------------------------------------------- CSR build

__global__ __launch_bounds__(256) void count_deg(const int* __restrict__ dst,
                                                 int* __restrict__ degi) {
    int e = blockIdx.x * 256 + threadIdx.x;
    if (e < NE) {
        int d = dst[e];
        if (d >= 0 && d < NN) atomicAdd(&degi[d], 1);
    }
}

// 1024 elements per block, 256 threads (4 contiguous elems/thread)
__global__ __launch_bounds__(256) void scan_bsum(const int* __restrict__ degi,
                                                 int* __restrict__ part) {
    __shared__ int s[256];
    int base = blockIdx.x * 1024 + threadIdx.x * 4;
    int tot = 0;
#pragma unroll
    for (int j = 0; j < 4; ++j) {
        int i = base + j;
        tot += (i < NN) ? degi[i] : 0;
    }
    s[threadIdx.x] = tot;
    __syncthreads();
    for (int off = 128; off > 0; off >>= 1) {
        if (threadIdx.x < off) s[threadIdx.x] += s[threadIdx.x + off];
        __syncthreads();
    }
    if (threadIdx.x == 0) part[blockIdx.x] = s[0];
}

__global__ void scan_part(int* __restrict__ part, int nb) {
    if (blockIdx.x == 0 && threadIdx.x == 0) {
        int run = 0;
        for (int i = 0; i < nb; ++i) {
            int v = part[i];
            part[i] = run;
            run += v;
        }
    }
}

__global__ __launch_bounds__(256) void scan_write(const int* __restrict__ degi,
                                                  const int* __restrict__ part,
                                                  int* __restrict__ rp) {
    __shared__ int s[256];
    const int tid = threadIdx.x;
    int base = blockIdx.x * 1024 + tid * 4;
    int d[4];
    int tot = 0;
#pragma unroll
    for (int j = 0; j < 4; ++j) {
        int i = base + j;
        d[j] = (i < NN) ? degi[i] : 0;
        tot += d[j];
    }
    s[tid] = tot;
    __syncthreads();
    // inclusive Hillis-Steele scan over thread totals
    for (int off = 1; off < 256; off <<= 1) {
        int v = (tid >= off) ? s[tid - off] : 0;
        __syncthreads();
        s[tid] += v;
        __syncthreads();
    }
    int run = part[blockIdx.x] + s[tid] - tot;  // exclusive prefix for this thread
#pragma unroll
    for (int j = 0; j < 4; ++j) {
        int i = base + j;
        if (i < NN) {
            rp[i] = run;
            if (i == NN - 1) rp[NN] = run + d[j];
            run += d[j];
        }
    }
}

__global__ __launch_bounds__(256) void make_dinv(const int* __restrict__ degi,
                                                 float* __restrict__ dinv) {
    int v = blockIdx.x * 256 + threadIdx.x;
    if (v < NN) dinv[v] = rsqrtf((float)(degi[v] + 1));  // +1 self-loop
}

__global__ __launch_bounds__(256) void scatter_csr(const int* __restrict__ src,
                                                   const int* __restrict__ dst,
                                                   const int* __restrict__ rp,
                                                   int* __restrict__ ctr,
                                                   const float* __restrict__ dinv,
                                                   uint2* __restrict__ csr) {
    int e = blockIdx.x * 256 + threadIdx.x;
    if (e >= NE) return;
    int s = src[e], d = dst[e];
    if (s < 0 || s >= NN || d < 0 || d >= NN) return;  // defensive: never OOB
    int pos = rp[d] + atomicAdd(&ctr[d], 1);
    if (pos < 0 || pos >= NE) return;
    uint2 v;
    v.x = (unsigned)s;
    v.y = __float_as_uint(dinv[s] * dinv[d]);
    csr[pos] = v;
}

// ---------------------------------------------------------------- GEMM 128x128 (fp32)
// C[M,128] = A[M,128] @ W[128,128]. W staged in LDS (64 KB).
// 256 threads: (ty,tx) = 16x16; each thread: 4 rows x 8 cols.
__global__ __launch_bounds__(256) void gemm128(const float* __restrict__ A,
                                               const float* __restrict__ W,
                                               float* __restrict__ C, int M) {
    __shared__ float Ws[FDIM * FDIM];
    {
        const float4* W4 = (const float4*)W;
        float4* S4 = (float4*)Ws;
        for (int i = threadIdx.x; i < FDIM * FDIM / 4; i += 256) S4[i] = W4[i];
    }
    __syncthreads();
    const int ty = threadIdx.x >> 4;
    const int tx = threadIdx.x & 15;
    const int row0 = blockIdx.x * 64 + ty * 4;
    int r[4];
#pragma unroll
    for (int i = 0; i < 4; ++i) r[i] = min(row0 + i, M - 1);

    float acc[4][8];
#pragma unroll
    for (int i = 0; i < 4; ++i)
#pragma unroll
        for (int j = 0; j < 8; ++j) acc[i][j] = 0.f;

    const float4* A4 = (const float4*)A;
    for (int k = 0; k < FDIM; k += 4) {
        float4 xv[4];
#pragma unroll
        for (int i = 0; i < 4; ++i) xv[i] = A4[r[i] * 32 + (k >> 2)];
#pragma unroll
        for (int kk = 0; kk < 4; ++kk) {
            const float4 wa = *(const float4*)(Ws + (k + kk) * FDIM + tx * 8);
            const float4 wb = *(const float4*)(Ws + (k + kk) * FDIM + tx * 8 + 4);
#pragma unroll
            for (int i = 0; i < 4; ++i) {
                const float xs = ((const float*)&xv[i])[kk];
                acc[i][0] = fmaf(xs, wa.x, acc[i][0]);
                acc[i][1] = fmaf(xs, wa.y, acc[i][1]);
                acc[i][2] = fmaf(xs, wa.z, acc[i][2]);
                acc[i][3] = fmaf(xs, wa.w, acc[i][3]);
                acc[i][4] = fmaf(xs, wb.x, acc[i][4]);
                acc[i][5] = fmaf(xs, wb.y, acc[i][5]);
                acc[i][6] = fmaf(xs, wb.z, acc[i][6]);
                acc[i][7] = fmaf(xs, wb.w, acc[i][7]);
            }
        }
    }
#pragma unroll
    for (int i = 0; i < 4; ++i) {
        int row = row0 + i;
        if (row < M) {
            float4 o0 = make_float4(acc[i][0], acc[i][1], acc[i][2], acc[i][3]);
            float4 o1 = make_float4(acc[i][4], acc[i][5], acc[i][6], acc[i][7]);
            *(float4*)(C + row * FDIM + tx * 8) = o0;
            *(float4*)(C + row * FDIM + tx * 8 + 4) = o1;
        }
    }
}

// ---------------------------------------------------------------- aggregation
// out[v] = relu( dinv[v]^2 * h[v] + sum_{e: dst=v} w_e * h[src_e] + b )
// 32 lanes per node (float4 each): 512B coalesced per edge. 8 nodes/block.
__global__ __launch_bounds__(256) void gcn_agg(const float* __restrict__ h,
                                               const uint2* __restrict__ csr,
                                               const int* __restrict__ rp,
                                               const float* __restrict__ dinv,
                                               const float* __restrict__ bias,
                                               float* __restrict__ out) {
    const int node = blockIdx.x * 8 + (threadIdx.x >> 5);
    const int fg = threadIdx.x & 31;
    const float4* __restrict__ h4 = (const float4*)h;

    const float di = dinv[node];
    const float sw = di * di;
    float4 a = h4[node * 32 + fg];
    float4 acc;
    acc.x = a.x * sw;
    acc.y = a.y * sw;
    acc.z = a.z * sw;
    acc.w = a.w * sw;

    int e0 = rp[node], e1 = rp[node + 1];
    if (e0 < 0) e0 = 0;
    if (e1 > NE) e1 = NE;
    for (int e = e0; e < e1; ++e) {
        const uint2 srw = csr[e];
        const float w = __uint_as_float(srw.y);
        const int s = (int)(srw.x & 0x7fffffffu) % NN;  // defensive
        const float4 hv = h4[s * 32 + fg];
        acc.x = fmaf(w, hv.x, acc.x);
        acc.y = fmaf(w, hv.y, acc.y);
        acc.z = fmaf(w, hv.z, acc.z);
        acc.w = fmaf(w, hv.w, acc.w);
    }
    const float4 b = ((const float4*)bias)[fg];
    float4 o;
    o.x = fmaxf(acc.x + b.x, 0.f);
    o.y = fmaxf(acc.y + b.y, 0.f);
    o.z = fmaxf(acc.z + b.z, 0.f);
    o.w = fmaxf(acc.w + b.w, 0.f);
    ((float4*)out)[node * 32 + fg] = o;
}

// ---------------------------------------------------------------- head + pool
__global__ __launch_bounds__(256) void final_pool(const float* __restrict__ h,
                                                  const float* __restrict__ Wl,
                                                  const float* __restrict__ bl,
                                                  const int* __restrict__ batch,
                                                  float* __restrict__ pool,
                                                  float* __restrict__ cnt) {
    __shared__ float Ws[FDIM * NACT];
    for (int i = threadIdx.x; i < FDIM * NACT; i += 256) Ws[i] = Wl[i];
    __syncthreads();
    const int v = blockIdx.x * 256 + threadIdx.x;
    if (v >= NN) return;
    float acc[NACT];
#pragma unroll
    for (int f = 0; f < NACT; ++f) acc[f] = bl[f];
    const float4* h4 = (const float4*)h + v * 32;
    for (int k4 = 0; k4 < 32; ++k4) {
        const float4 xv = h4[k4];
#pragma unroll
        for (int f = 0; f < NACT; ++f) {
            acc[f] = fmaf(xv.x, Ws[(k4 * 4 + 0) * NACT + f], acc[f]);
            acc[f] = fmaf(xv.y, Ws[(k4 * 4 + 1) * NACT + f], acc[f]);
            acc[f] = fmaf(xv.z, Ws[(k4 * 4 + 2) * NACT + f], acc[f]);
            acc[f] = fmaf(xv.w, Ws[(k4 * 4 + 3) * NACT + f], acc[f]);
        }
    }
    int g = batch[v];
    if (g < 0) g = 0;
    if (g >= NG) g = NG - 1;  // defensive
#pragma unroll
    for (int f = 0; f < NACT; ++f) atomicAdd(&pool[g * NACT + f], tanhf(acc[f]));
    atomicAdd(&cnt[g], 1.0f);
}

__global__ __launch_bounds__(256) void finalize(const float* __restrict__ pool,
                                                const float* __restrict__ cnt,
                                                float* __restrict__ out) {
    int i = blockIdx.x * 256 + threadIdx.x;
    if (i < NG * NACT) out[i] = pool[i] / fmaxf(cnt[i >> 3], 1.0f);
}

// ---------------------------------------------------------------- launch

extern "C" void kernel_launch(void* const* d_in, const int* in_sizes, int n_in,
                              void* d_out, int out_size, void* d_ws, size_t ws_size,
                              hipStream_t stream) {
    const float* x = (const float*)d_in[0];
    const int* ei = (const int*)d_in[1];
    const int* batch = (const int*)d_in[2];
    const float* W1 = (const float*)d_in[3];
    const float* b1 = (const float*)d_in[4];
    const float* W2 = (const float*)d_in[5];
    const float* b2 = (const float*)d_in[6];
    const float* W3 = (const float*)d_in[7];
    const float* b3 = (const float*)d_in[8];
    const float* Wl = (const float*)d_in[9];
    const float* bl = (const float*)d_in[10];

    const int* src = ei;
    const int* dst = ei + NE;

    char* p = (char*)d_ws;
    auto alloc = [&](size_t bytes) {
        void* r = (void*)p;
        p += (bytes + 255) & ~(size_t)255;
        return r;
    };
    float* hbuf = (float*)alloc((size_t)NN * FDIM * 4);  // 51.2 MB
    float* abuf = (float*)alloc((size_t)NN * FDIM * 4);  // 51.2 MB
    uint2* csr  = (uint2*)alloc((size_t)NE * 8);         // 12.8 MB
    int* degi   = (int*)alloc(NN * 4);
    int* rp     = (int*)alloc((NN + 1) * 4);
    int* ctr    = (int*)alloc(NN * 4);
    float* dinv = (float*)alloc(NN * 4);
    int* part   = (int*)alloc(4096);
    float* pool = (float*)alloc(NG * NACT * 4);
    float* cnt  = (float*)alloc(NG * 4);

    hipMemsetAsync(degi, 0, NN * 4, stream);
    hipMemsetAsync(ctr, 0, NN * 4, stream);
    hipMemsetAsync(pool, 0, NG * NACT * 4, stream);
    hipMemsetAsync(cnt, 0, NG * 4, stream);

    const int NB_SCAN = (NN + 1023) / 1024;  // 98
    count_deg<<<(NE + 255) / 256, 256, 0, stream>>>(dst, degi);
    scan_bsum<<<NB_SCAN, 256, 0, stream>>>(degi, part);
    scan_part<<<1, 64, 0, stream>>>(part, NB_SCAN);
    scan_write<<<NB_SCAN, 256, 0, stream>>>(degi, part, rp);
    make_dinv<<<(NN + 255) / 256, 256, 0, stream>>>(degi, dinv);
    scatter_csr<<<(NE + 255) / 256, 256, 0, stream>>>(src, dst, rp, ctr, dinv, csr);

    gemm128<<<(NN + 63) / 64, 256, 0, stream>>>(x, W1, hbuf, NN);
    gcn_agg<<<NN / 8, 256, 0, stream>>>(hbuf, csr, rp, dinv, b1, abuf);
    gemm128<<<(NN + 63) / 64, 256, 0, stream>>>(abuf, W2, hbuf, NN);
    gcn_agg<<<NN / 8, 256, 0, stream>>>(hbuf, csr, rp, dinv, b2, abuf);
    gemm128<<<(NN + 63) / 64, 256, 0, stream>>>(abuf, W3, hbuf, NN);
    gcn_agg<<<NN / 8, 256, 0, stream>>>(hbuf, csr, rp, dinv, b3, abuf);

    final_pool<<<(NN + 255) / 256, 256, 0, stream>>>(abuf, Wl, bl, batch, pool, cnt);
    finalize<<<(NG * NACT + 255) / 256, 256, 0, stream>>>(pool, cnt, (float*)d_out);
}

// Round 4
// 851.463 us; speedup vs baseline: 1.1320x; 1.1320x over previous
//
#include <hip/hip_runtime.h>

#define NN 100000
#define NE 1600000
#define FDIM 128
#define NACT 8
#define NG 1024

// ---------------------------------------------------------------- CSR build

__global__ __launch_bounds__(256) void count_deg(const int* __restrict__ dst,
                                                 int* __restrict__ degi) {
    int e = blockIdx.x * 256 + threadIdx.x;
    if (e < NE) {
        int d = dst[e];
        if (d >= 0 && d < NN) atomicAdd(&degi[d], 1);
    }
}

// 1024 elements per block, 256 threads (4 contiguous elems/thread)
__global__ __launch_bounds__(256) void scan_bsum(const int* __restrict__ degi,
                                                 int* __restrict__ part) {
    __shared__ int s[256];
    int base = blockIdx.x * 1024 + threadIdx.x * 4;
    int tot = 0;
#pragma unroll
    for (int j = 0; j < 4; ++j) {
        int i = base + j;
        tot += (i < NN) ? degi[i] : 0;
    }
    s[threadIdx.x] = tot;
    __syncthreads();
    for (int off = 128; off > 0; off >>= 1) {
        if (threadIdx.x < off) s[threadIdx.x] += s[threadIdx.x + off];
        __syncthreads();
    }
    if (threadIdx.x == 0) part[blockIdx.x] = s[0];
}

__global__ void scan_part(int* __restrict__ part, int nb) {
    if (blockIdx.x == 0 && threadIdx.x == 0) {
        int run = 0;
        for (int i = 0; i < nb; ++i) {
            int v = part[i];
            part[i] = run;
            run += v;
        }
    }
}

__global__ __launch_bounds__(256) void scan_write(const int* __restrict__ degi,
                                                  const int* __restrict__ part,
                                                  int* __restrict__ rp) {
    __shared__ int s[256];
    const int tid = threadIdx.x;
    int base = blockIdx.x * 1024 + tid * 4;
    int d[4];
    int tot = 0;
#pragma unroll
    for (int j = 0; j < 4; ++j) {
        int i = base + j;
        d[j] = (i < NN) ? degi[i] : 0;
        tot += d[j];
    }
    s[tid] = tot;
    __syncthreads();
    // inclusive Hillis-Steele scan over thread totals
    for (int off = 1; off < 256; off <<= 1) {
        int v = (tid >= off) ? s[tid - off] : 0;
        __syncthreads();
        s[tid] += v;
        __syncthreads();
    }
    int run = part[blockIdx.x] + s[tid] - tot;  // exclusive prefix for this thread
#pragma unroll
    for (int j = 0; j < 4; ++j) {
        int i = base + j;
        if (i < NN) {
            rp[i] = run;
            if (i == NN - 1) rp[NN] = run + d[j];
            run += d[j];
        }
    }
}

__global__ __launch_bounds__(256) void make_dinv(const int* __restrict__ degi,
                                                 float* __restrict__ dinv) {
    int v = blockIdx.x * 256 + threadIdx.x;
    if (v < NN) dinv[v] = rsqrtf((float)(degi[v] + 1));  // +1 self-loop
}

__global__ __launch_bounds__(256) void scatter_csr(const int* __restrict__ src,
                                                   const int* __restrict__ dst,
                                                   const int* __restrict__ rp,
                                                   int* __restrict__ ctr,
                                                   const float* __restrict__ dinv,
                                                   uint2* __restrict__ csr) {
    int e = blockIdx.x * 256 + threadIdx.x;
    if (e >= NE) return;
    int s = src[e], d = dst[e];
    if (s < 0 || s >= NN || d < 0 || d >= NN) return;  // defensive: never OOB
    int pos = rp[d] + atomicAdd(&ctr[d], 1);
    if (pos < 0 || pos >= NE) return;
    uint2 v;
    v.x = (unsigned)s;
    v.y = __float_as_uint(dinv[s] * dinv[d]);
    csr[pos] = v;
}

// ---------------------------------------------------------------- GEMM 128x128 (fp32)
// C[M,128] = A[M,128] @ W[128,128]. W staged in LDS (64 KB).
// 256 threads: (ty,tx) = 16x16; each thread: 4 rows x 8 cols.
__global__ __launch_bounds__(256) void gemm128(const float* __restrict__ A,
                                               const float* __restrict__ W,
                                               float* __restrict__ C, int M) {
    __shared__ float Ws[FDIM * FDIM];
    {
        const float4* W4 = (const float4*)W;
        float4* S4 = (float4*)Ws;
        for (int i = threadIdx.x; i < FDIM * FDIM / 4; i += 256) S4[i] = W4[i];
    }
    __syncthreads();
    const int ty = threadIdx.x >> 4;
    const int tx = threadIdx.x & 15;
    const int row0 = blockIdx.x * 64 + ty * 4;
    int r[4];
#pragma unroll
    for (int i = 0; i < 4; ++i) r[i] = min(row0 + i, M - 1);

    float acc[4][8];
#pragma unroll
    for (int i = 0; i < 4; ++i)
#pragma unroll
        for (int j = 0; j < 8; ++j) acc[i][j] = 0.f;

    const float4* A4 = (const float4*)A;
    for (int k = 0; k < FDIM; k += 4) {
        float4 xv[4];
#pragma unroll
        for (int i = 0; i < 4; ++i) xv[i] = A4[r[i] * 32 + (k >> 2)];
#pragma unroll
        for (int kk = 0; kk < 4; ++kk) {
            const float4 wa = *(const float4*)(Ws + (k + kk) * FDIM + tx * 8);
            const float4 wb = *(const float4*)(Ws + (k + kk) * FDIM + tx * 8 + 4);
#pragma unroll
            for (int i = 0; i < 4; ++i) {
                const float xs = ((const float*)&xv[i])[kk];
                acc[i][0] = fmaf(xs, wa.x, acc[i][0]);
                acc[i][1] = fmaf(xs, wa.y, acc[i][1]);
                acc[i][2] = fmaf(xs, wa.z, acc[i][2]);
                acc[i][3] = fmaf(xs, wa.w, acc[i][3]);
                acc[i][4] = fmaf(xs, wb.x, acc[i][4]);
                acc[i][5] = fmaf(xs, wb.y, acc[i][5]);
                acc[i][6] = fmaf(xs, wb.z, acc[i][6]);
                acc[i][7] = fmaf(xs, wb.w, acc[i][7]);
            }
        }
    }
#pragma unroll
    for (int i = 0; i < 4; ++i) {
        int row = row0 + i;
        if (row < M) {
            float4 o0 = make_float4(acc[i][0], acc[i][1], acc[i][2], acc[i][3]);
            float4 o1 = make_float4(acc[i][4], acc[i][5], acc[i][6], acc[i][7]);
            *(float4*)(C + row * FDIM + tx * 8) = o0;
            *(float4*)(C + row * FDIM + tx * 8 + 4) = o1;
        }
    }
}

// ---------------------------------------------------------------- aggregation
// out[v] = relu( dinv[v]^2 * h[v] + sum_{e: dst=v} w_e * h[src_e] + b )
// 32 lanes per node (float4 each): 512B coalesced per edge. 8 nodes/block.
__global__ __launch_bounds__(256) void gcn_agg(const float* __restrict__ h,
                                               const uint2* __restrict__ csr,
                                               const int* __restrict__ rp,
                                               const float* __restrict__ dinv,
                                               const float* __restrict__ bias,
                                               float* __restrict__ out) {
    const int node = blockIdx.x * 8 + (threadIdx.x >> 5);
    const int fg = threadIdx.x & 31;
    const float4* __restrict__ h4 = (const float4*)h;

    const float di = dinv[node];
    const float sw = di * di;
    float4 a = h4[node * 32 + fg];
    float4 acc;
    acc.x = a.x * sw;
    acc.y = a.y * sw;
    acc.z = a.z * sw;
    acc.w = a.w * sw;

    int e0 = rp[node], e1 = rp[node + 1];
    if (e0 < 0) e0 = 0;
    if (e1 > NE) e1 = NE;
    for (int e = e0; e < e1; ++e) {
        const uint2 srw = csr[e];
        const float w = __uint_as_float(srw.y);
        const int s = (int)(srw.x & 0x7fffffffu) % NN;  // defensive
        const float4 hv = h4[s * 32 + fg];
        acc.x = fmaf(w, hv.x, acc.x);
        acc.y = fmaf(w, hv.y, acc.y);
        acc.z = fmaf(w, hv.z, acc.z);
        acc.w = fmaf(w, hv.w, acc.w);
    }
    const float4 b = ((const float4*)bias)[fg];
    float4 o;
    o.x = fmaxf(acc.x + b.x, 0.f);
    o.y = fmaxf(acc.y + b.y, 0.f);
    o.z = fmaxf(acc.z + b.z, 0.f);
    o.w = fmaxf(acc.w + b.w, 0.f);
    ((float4*)out)[node * 32 + fg] = o;
}

// ---------------------------------------------------------------- head + pool
// One block per graph. batch is sorted -> binary search node range, then
// per-thread dot(h[v], Wl)+tanh accumulated in registers, LDS tree-reduce,
// direct store. ZERO global atomics (old version was 64-way same-address
// atomic serialization at 141 us).
__global__ __launch_bounds__(256) void head_pool(const float* __restrict__ h,
                                                 const float* __restrict__ Wl,
                                                 const float* __restrict__ bl,
                                                 const int* __restrict__ batch,
                                                 float* __restrict__ out) {
    const int g = blockIdx.x;
    const int tid = threadIdx.x;

    // lower_bound(batch, g) and upper_bound(batch, g) — all threads redundantly
    int lo = 0, hi = NN;
    while (lo < hi) {
        int mid = (lo + hi) >> 1;
        if (batch[mid] < g) lo = mid + 1; else hi = mid;
    }
    const int start = lo;
    hi = NN;
    while (lo < hi) {
        int mid = (lo + hi) >> 1;
        if (batch[mid] <= g) lo = mid + 1; else hi = mid;
    }
    const int end = lo;

    __shared__ float Ws[FDIM * NACT];  // 4 KB
    for (int i = tid; i < FDIM * NACT; i += 256) Ws[i] = Wl[i];
    __syncthreads();

    float acc[NACT];
#pragma unroll
    for (int f = 0; f < NACT; ++f) acc[f] = 0.f;

    for (int v = start + tid; v < end; v += 256) {
        float o[NACT];
#pragma unroll
        for (int f = 0; f < NACT; ++f) o[f] = bl[f];
        const float4* h4 = (const float4*)h + (size_t)v * 32;
        for (int k4 = 0; k4 < 32; ++k4) {
            const float4 xv = h4[k4];
#pragma unroll
            for (int f = 0; f < NACT; ++f) {
                o[f] = fmaf(xv.x, Ws[(k4 * 4 + 0) * NACT + f], o[f]);
                o[f] = fmaf(xv.y, Ws[(k4 * 4 + 1) * NACT + f], o[f]);
                o[f] = fmaf(xv.z, Ws[(k4 * 4 + 2) * NACT + f], o[f]);
                o[f] = fmaf(xv.w, Ws[(k4 * 4 + 3) * NACT + f], o[f]);
            }
        }
#pragma unroll
        for (int f = 0; f < NACT; ++f) acc[f] += tanhf(o[f]);
    }

    __shared__ float red[256 * NACT];  // 8 KB
#pragma unroll
    for (int f = 0; f < NACT; ++f) red[tid * NACT + f] = acc[f];
    __syncthreads();
    for (int off = 128; off > 0; off >>= 1) {
        if (tid < off) {
#pragma unroll
            for (int f = 0; f < NACT; ++f)
                red[tid * NACT + f] += red[(tid + off) * NACT + f];
        }
        __syncthreads();
    }
    if (tid < NACT) {
        const float inv = 1.0f / fmaxf((float)(end - start), 1.0f);
        out[g * NACT + tid] = red[tid] * inv;
    }
}

// ---------------------------------------------------------------- launch

extern "C" void kernel_launch(void* const* d_in, const int* in_sizes, int n_in,
                              void* d_out, int out_size, void* d_ws, size_t ws_size,
                              hipStream_t stream) {
    const float* x = (const float*)d_in[0];
    const int* ei = (const int*)d_in[1];
    const int* batch = (const int*)d_in[2];
    const float* W1 = (const float*)d_in[3];
    const float* b1 = (const float*)d_in[4];
    const float* W2 = (const float*)d_in[5];
    const float* b2 = (const float*)d_in[6];
    const float* W3 = (const float*)d_in[7];
    const float* b3 = (const float*)d_in[8];
    const float* Wl = (const float*)d_in[9];
    const float* bl = (const float*)d_in[10];

    const int* src = ei;
    const int* dst = ei + NE;

    char* p = (char*)d_ws;
    auto alloc = [&](size_t bytes) {
        void* r = (void*)p;
        p += (bytes + 255) & ~(size_t)255;
        return r;
    };
    float* hbuf = (float*)alloc((size_t)NN * FDIM * 4);  // 51.2 MB
    float* abuf = (float*)alloc((size_t)NN * FDIM * 4);  // 51.2 MB
    uint2* csr  = (uint2*)alloc((size_t)NE * 8);         // 12.8 MB
    int* degi   = (int*)alloc(NN * 4);
    int* rp     = (int*)alloc((NN + 1) * 4);
    int* ctr    = (int*)alloc(NN * 4);
    float* dinv = (float*)alloc(NN * 4);
    int* part   = (int*)alloc(4096);

    hipMemsetAsync(degi, 0, NN * 4, stream);
    hipMemsetAsync(ctr, 0, NN * 4, stream);

    const int NB_SCAN = (NN + 1023) / 1024;  // 98
    count_deg<<<(NE + 255) / 256, 256, 0, stream>>>(dst, degi);
    scan_bsum<<<NB_SCAN, 256, 0, stream>>>(degi, part);
    scan_part<<<1, 64, 0, stream>>>(part, NB_SCAN);
    scan_write<<<NB_SCAN, 256, 0, stream>>>(degi, part, rp);
    make_dinv<<<(NN + 255) / 256, 256, 0, stream>>>(degi, dinv);
    scatter_csr<<<(NE + 255) / 256, 256, 0, stream>>>(src, dst, rp, ctr, dinv, csr);

    gemm128<<<(NN + 63) / 64, 256, 0, stream>>>(x, W1, hbuf, NN);
    gcn_agg<<<NN / 8, 256, 0, stream>>>(hbuf, csr, rp, dinv, b1, abuf);
    gemm128<<<(NN + 63) / 64, 256, 0, stream>>>(abuf, W2, hbuf, NN);
    gcn_agg<<<NN / 8, 256, 0, stream>>>(hbuf, csr, rp, dinv, b2, abuf);
    gemm128<<<(NN + 63) / 64, 256, 0, stream>>>(abuf, W3, hbuf, NN);
    gcn_agg<<<NN / 8, 256, 0, stream>>>(hbuf, csr, rp, dinv, b3, abuf);

    head_pool<<<NG, 256, 0, stream>>>(abuf, Wl, bl, batch, (float*)d_out);
}

// Round 5
// 766.268 us; speedup vs baseline: 1.2578x; 1.1112x over previous
//
#include <hip/hip_runtime.h>
#include <hip/hip_fp16.h>

#define NN 100000
#define NE 1600000
#define FDIM 128
#define NACT 8
#define NG 1024

// ---------------------------------------------------------------- CSR build

__global__ __launch_bounds__(256) void count_deg(const int* __restrict__ dst,
                                                 int* __restrict__ degi) {
    int e = blockIdx.x * 256 + threadIdx.x;
    if (e < NE) {
        int d = dst[e];
        if (d >= 0 && d < NN) atomicAdd(&degi[d], 1);
    }
}

// 1024 elements per block, 256 threads (4 contiguous elems/thread)
__global__ __launch_bounds__(256) void scan_bsum(const int* __restrict__ degi,
                                                 int* __restrict__ part) {
    __shared__ int s[256];
    int base = blockIdx.x * 1024 + threadIdx.x * 4;
    int tot = 0;
#pragma unroll
    for (int j = 0; j < 4; ++j) {
        int i = base + j;
        tot += (i < NN) ? degi[i] : 0;
    }
    s[threadIdx.x] = tot;
    __syncthreads();
    for (int off = 128; off > 0; off >>= 1) {
        if (threadIdx.x < off) s[threadIdx.x] += s[threadIdx.x + off];
        __syncthreads();
    }
    if (threadIdx.x == 0) part[blockIdx.x] = s[0];
}

__global__ void scan_part(int* __restrict__ part, int nb) {
    if (blockIdx.x == 0 && threadIdx.x == 0) {
        int run = 0;
        for (int i = 0; i < nb; ++i) {
            int v = part[i];
            part[i] = run;
            run += v;
        }
    }
}

__global__ __launch_bounds__(256) void scan_write(const int* __restrict__ degi,
                                                  const int* __restrict__ part,
                                                  int* __restrict__ rp) {
    __shared__ int s[256];
    const int tid = threadIdx.x;
    int base = blockIdx.x * 1024 + tid * 4;
    int d[4];
    int tot = 0;
#pragma unroll
    for (int j = 0; j < 4; ++j) {
        int i = base + j;
        d[j] = (i < NN) ? degi[i] : 0;
        tot += d[j];
    }
    s[tid] = tot;
    __syncthreads();
    // inclusive Hillis-Steele scan over thread totals
    for (int off = 1; off < 256; off <<= 1) {
        int v = (tid >= off) ? s[tid - off] : 0;
        __syncthreads();
        s[tid] += v;
        __syncthreads();
    }
    int run = part[blockIdx.x] + s[tid] - tot;  // exclusive prefix for this thread
#pragma unroll
    for (int j = 0; j < 4; ++j) {
        int i = base + j;
        if (i < NN) {
            rp[i] = run;
            if (i == NN - 1) rp[NN] = run + d[j];
            run += d[j];
        }
    }
}

__global__ __launch_bounds__(256) void make_dinv(const int* __restrict__ degi,
                                                 float* __restrict__ dinv) {
    int v = blockIdx.x * 256 + threadIdx.x;
    if (v < NN) dinv[v] = rsqrtf((float)(degi[v] + 1));  // +1 self-loop
}

__global__ __launch_bounds__(256) void scatter_csr(const int* __restrict__ src,
                                                   const int* __restrict__ dst,
                                                   const int* __restrict__ rp,
                                                   int* __restrict__ ctr,
                                                   const float* __restrict__ dinv,
                                                   uint2* __restrict__ csr) {
    int e = blockIdx.x * 256 + threadIdx.x;
    if (e >= NE) return;
    int s = src[e], d = dst[e];
    if (s < 0 || s >= NN || d < 0 || d >= NN) return;  // defensive: never OOB
    int pos = rp[d] + atomicAdd(&ctr[d], 1);
    if (pos < 0 || pos >= NE) return;
    uint2 v;
    v.x = (unsigned)s;
    v.y = __float_as_uint(dinv[s] * dinv[d]);
    csr[pos] = v;
}

// ---------------------------------------------------------------- GEMM 128x128
// C[M,128] (fp16) = A[M,128] (fp32) @ W[128,128] (fp32). W staged in LDS.
// 256 threads: (ty,tx) = 16x16; each thread: 4 rows x 8 cols.
// fp16 output: halves the gather row size for gcn_agg (256 B vs 512 B).
__global__ __launch_bounds__(256) void gemm128(const float* __restrict__ A,
                                               const float* __restrict__ W,
                                               __half* __restrict__ C, int M) {
    __shared__ float Ws[FDIM * FDIM];
    {
        const float4* W4 = (const float4*)W;
        float4* S4 = (float4*)Ws;
        for (int i = threadIdx.x; i < FDIM * FDIM / 4; i += 256) S4[i] = W4[i];
    }
    __syncthreads();
    const int ty = threadIdx.x >> 4;
    const int tx = threadIdx.x & 15;
    const int row0 = blockIdx.x * 64 + ty * 4;
    int r[4];
#pragma unroll
    for (int i = 0; i < 4; ++i) r[i] = min(row0 + i, M - 1);

    float acc[4][8];
#pragma unroll
    for (int i = 0; i < 4; ++i)
#pragma unroll
        for (int j = 0; j < 8; ++j) acc[i][j] = 0.f;

    const float4* A4 = (const float4*)A;
    for (int k = 0; k < FDIM; k += 4) {
        float4 xv[4];
#pragma unroll
        for (int i = 0; i < 4; ++i) xv[i] = A4[r[i] * 32 + (k >> 2)];
#pragma unroll
        for (int kk = 0; kk < 4; ++kk) {
            const float4 wa = *(const float4*)(Ws + (k + kk) * FDIM + tx * 8);
            const float4 wb = *(const float4*)(Ws + (k + kk) * FDIM + tx * 8 + 4);
#pragma unroll
            for (int i = 0; i < 4; ++i) {
                const float xs = ((const float*)&xv[i])[kk];
                acc[i][0] = fmaf(xs, wa.x, acc[i][0]);
                acc[i][1] = fmaf(xs, wa.y, acc[i][1]);
                acc[i][2] = fmaf(xs, wa.z, acc[i][2]);
                acc[i][3] = fmaf(xs, wa.w, acc[i][3]);
                acc[i][4] = fmaf(xs, wb.x, acc[i][4]);
                acc[i][5] = fmaf(xs, wb.y, acc[i][5]);
                acc[i][6] = fmaf(xs, wb.z, acc[i][6]);
                acc[i][7] = fmaf(xs, wb.w, acc[i][7]);
            }
        }
    }
#pragma unroll
    for (int i = 0; i < 4; ++i) {
        int row = row0 + i;
        if (row < M) {
            __half2 h0 = __floats2half2_rn(acc[i][0], acc[i][1]);
            __half2 h1 = __floats2half2_rn(acc[i][2], acc[i][3]);
            __half2 h2 = __floats2half2_rn(acc[i][4], acc[i][5]);
            __half2 h3 = __floats2half2_rn(acc[i][6], acc[i][7]);
            uint4 pack;
            pack.x = *(unsigned*)&h0;
            pack.y = *(unsigned*)&h1;
            pack.z = *(unsigned*)&h2;
            pack.w = *(unsigned*)&h3;
            *(uint4*)(C + (size_t)row * FDIM + tx * 8) = pack;
        }
    }
}

// ---------------------------------------------------------------- aggregation
// out[v] = relu( dinv[v]^2 * h[v] + sum_{e: dst=v} w_e * h[src_e] + b )
// h is fp16: 32 lanes per node, 8 B (4 halves) per lane -> 256 B/row gather.
// Accumulation in fp32. 8 nodes/block.
__device__ inline float4 h16x4_to_f4(uint2 u) {
    __half2 a = *(__half2*)&u.x;
    __half2 b = *(__half2*)&u.y;
    float2 fa = __half22float2(a);
    float2 fb = __half22float2(b);
    return make_float4(fa.x, fa.y, fb.x, fb.y);
}

__global__ __launch_bounds__(256) void gcn_agg(const __half* __restrict__ h,
                                               const uint2* __restrict__ csr,
                                               const int* __restrict__ rp,
                                               const float* __restrict__ dinv,
                                               const float* __restrict__ bias,
                                               float* __restrict__ out) {
    const int node = blockIdx.x * 8 + (threadIdx.x >> 5);
    const int fg = threadIdx.x & 31;
    const uint2* __restrict__ h8 = (const uint2*)h;  // 4 halves per uint2

    const float di = dinv[node];
    const float sw = di * di;
    float4 a = h16x4_to_f4(h8[node * 32 + fg]);
    float4 acc;
    acc.x = a.x * sw;
    acc.y = a.y * sw;
    acc.z = a.z * sw;
    acc.w = a.w * sw;

    int e0 = rp[node], e1 = rp[node + 1];
    if (e0 < 0) e0 = 0;
    if (e1 > NE) e1 = NE;
    for (int e = e0; e < e1; ++e) {
        const uint2 srw = csr[e];
        const float w = __uint_as_float(srw.y);
        const int s = (int)(srw.x & 0x7fffffffu) % NN;  // defensive
        const float4 hv = h16x4_to_f4(h8[s * 32 + fg]);
        acc.x = fmaf(w, hv.x, acc.x);
        acc.y = fmaf(w, hv.y, acc.y);
        acc.z = fmaf(w, hv.z, acc.z);
        acc.w = fmaf(w, hv.w, acc.w);
    }
    const float4 b = ((const float4*)bias)[fg];
    float4 o;
    o.x = fmaxf(acc.x + b.x, 0.f);
    o.y = fmaxf(acc.y + b.y, 0.f);
    o.z = fmaxf(acc.z + b.z, 0.f);
    o.w = fmaxf(acc.w + b.w, 0.f);
    ((float4*)out)[node * 32 + fg] = o;
}

// ---------------------------------------------------------------- head + pool
// One block per graph. batch is sorted -> binary search node range, then
// per-thread dot(h[v], Wl)+tanh accumulated in registers, LDS tree-reduce,
// direct store. ZERO global atomics.
__global__ __launch_bounds__(256) void head_pool(const float* __restrict__ h,
                                                 const float* __restrict__ Wl,
                                                 const float* __restrict__ bl,
                                                 const int* __restrict__ batch,
                                                 float* __restrict__ out) {
    const int g = blockIdx.x;
    const int tid = threadIdx.x;

    int lo = 0, hi = NN;
    while (lo < hi) {
        int mid = (lo + hi) >> 1;
        if (batch[mid] < g) lo = mid + 1; else hi = mid;
    }
    const int start = lo;
    hi = NN;
    while (lo < hi) {
        int mid = (lo + hi) >> 1;
        if (batch[mid] <= g) lo = mid + 1; else hi = mid;
    }
    const int end = lo;

    __shared__ float Ws[FDIM * NACT];  // 4 KB
    for (int i = tid; i < FDIM * NACT; i += 256) Ws[i] = Wl[i];
    __syncthreads();

    float acc[NACT];
#pragma unroll
    for (int f = 0; f < NACT; ++f) acc[f] = 0.f;

    for (int v = start + tid; v < end; v += 256) {
        float o[NACT];
#pragma unroll
        for (int f = 0; f < NACT; ++f) o[f] = bl[f];
        const float4* h4 = (const float4*)h + (size_t)v * 32;
        for (int k4 = 0; k4 < 32; ++k4) {
            const float4 xv = h4[k4];
#pragma unroll
            for (int f = 0; f < NACT; ++f) {
                o[f] = fmaf(xv.x, Ws[(k4 * 4 + 0) * NACT + f], o[f]);
                o[f] = fmaf(xv.y, Ws[(k4 * 4 + 1) * NACT + f], o[f]);
                o[f] = fmaf(xv.z, Ws[(k4 * 4 + 2) * NACT + f], o[f]);
                o[f] = fmaf(xv.w, Ws[(k4 * 4 + 3) * NACT + f], o[f]);
            }
        }
#pragma unroll
        for (int f = 0; f < NACT; ++f) acc[f] += tanhf(o[f]);
    }

    __shared__ float red[256 * NACT];  // 8 KB
#pragma unroll
    for (int f = 0; f < NACT; ++f) red[tid * NACT + f] = acc[f];
    __syncthreads();
    for (int off = 128; off > 0; off >>= 1) {
        if (tid < off) {
#pragma unroll
            for (int f = 0; f < NACT; ++f)
                red[tid * NACT + f] += red[(tid + off) * NACT + f];
        }
        __syncthreads();
    }
    if (tid < NACT) {
        const float inv = 1.0f / fmaxf((float)(end - start), 1.0f);
        out[g * NACT + tid] = red[tid] * inv;
    }
}

// ---------------------------------------------------------------- launch

extern "C" void kernel_launch(void* const* d_in, const int* in_sizes, int n_in,
                              void* d_out, int out_size, void* d_ws, size_t ws_size,
                              hipStream_t stream) {
    const float* x = (const float*)d_in[0];
    const int* ei = (const int*)d_in[1];
    const int* batch = (const int*)d_in[2];
    const float* W1 = (const float*)d_in[3];
    const float* b1 = (const float*)d_in[4];
    const float* W2 = (const float*)d_in[5];
    const float* b2 = (const float*)d_in[6];
    const float* W3 = (const float*)d_in[7];
    const float* b3 = (const float*)d_in[8];
    const float* Wl = (const float*)d_in[9];
    const float* bl = (const float*)d_in[10];

    const int* src = ei;
    const int* dst = ei + NE;

    char* p = (char*)d_ws;
    auto alloc = [&](size_t bytes) {
        void* r = (void*)p;
        p += (bytes + 255) & ~(size_t)255;
        return r;
    };
    __half* hbuf = (__half*)alloc((size_t)NN * FDIM * 2);  // 25.6 MB (fp16)
    float* abuf  = (float*)alloc((size_t)NN * FDIM * 4);   // 51.2 MB
    uint2* csr   = (uint2*)alloc((size_t)NE * 8);          // 12.8 MB
    int* degi    = (int*)alloc(NN * 4);
    int* rp      = (int*)alloc((NN + 1) * 4);
    int* ctr     = (int*)alloc(NN * 4);
    float* dinv  = (float*)alloc(NN * 4);
    int* part    = (int*)alloc(4096);

    hipMemsetAsync(degi, 0, NN * 4, stream);
    hipMemsetAsync(ctr, 0, NN * 4, stream);

    const int NB_SCAN = (NN + 1023) / 1024;  // 98
    count_deg<<<(NE + 255) / 256, 256, 0, stream>>>(dst, degi);
    scan_bsum<<<NB_SCAN, 256, 0, stream>>>(degi, part);
    scan_part<<<1, 64, 0, stream>>>(part, NB_SCAN);
    scan_write<<<NB_SCAN, 256, 0, stream>>>(degi, part, rp);
    make_dinv<<<(NN + 255) / 256, 256, 0, stream>>>(degi, dinv);
    scatter_csr<<<(NE + 255) / 256, 256, 0, stream>>>(src, dst, rp, ctr, dinv, csr);

    gemm128<<<(NN + 63) / 64, 256, 0, stream>>>(x, W1, hbuf, NN);
    gcn_agg<<<NN / 8, 256, 0, stream>>>(hbuf, csr, rp, dinv, b1, abuf);
    gemm128<<<(NN + 63) / 64, 256, 0, stream>>>(abuf, W2, hbuf, NN);
    gcn_agg<<<NN / 8, 256, 0, stream>>>(hbuf, csr, rp, dinv, b2, abuf);
    gemm128<<<(NN + 63) / 64, 256, 0, stream>>>(abuf, W3, hbuf, NN);
    gcn_agg<<<NN / 8, 256, 0, stream>>>(hbuf, csr, rp, dinv, b3, abuf);

    head_pool<<<NG, 256, 0, stream>>>(abuf, Wl, bl, batch, (float*)d_out);
}

// Round 7
// 653.338 us; speedup vs baseline: 1.4753x; 1.1729x over previous
//
#include <hip/hip_runtime.h>
#include <hip/hip_fp16.h>

#define NN 100000
#define NE 1600000
#define FDIM 128
#define NACT 8
#define NG 1024

// ---------------------------------------------------------------- CSR build

__global__ __launch_bounds__(256) void count_deg(const int* __restrict__ dst,
                                                 int* __restrict__ degi) {
    int e = blockIdx.x * 256 + threadIdx.x;
    if (e < NE) {
        int d = dst[e];
        if (d >= 0 && d < NN) atomicAdd(&degi[d], 1);
    }
}

// 1024 elements per block, 256 threads (4 contiguous elems/thread)
__global__ __launch_bounds__(256) void scan_bsum(const int* __restrict__ degi,
                                                 int* __restrict__ part) {
    __shared__ int s[256];
    int base = blockIdx.x * 1024 + threadIdx.x * 4;
    int tot = 0;
#pragma unroll
    for (int j = 0; j < 4; ++j) {
        int i = base + j;
        tot += (i < NN) ? degi[i] : 0;
    }
    s[threadIdx.x] = tot;
    __syncthreads();
    for (int off = 128; off > 0; off >>= 1) {
        if (threadIdx.x < off) s[threadIdx.x] += s[threadIdx.x + off];
        __syncthreads();
    }
    if (threadIdx.x == 0) part[blockIdx.x] = s[0];
}

__global__ void scan_part(int* __restrict__ part, int nb) {
    if (blockIdx.x == 0 && threadIdx.x == 0) {
        int run = 0;
        for (int i = 0; i < nb; ++i) {
            int v = part[i];
            part[i] = run;
            run += v;
        }
    }
}

__global__ __launch_bounds__(256) void scan_write(const int* __restrict__ degi,
                                                  const int* __restrict__ part,
                                                  int* __restrict__ rp) {
    __shared__ int s[256];
    const int tid = threadIdx.x;
    int base = blockIdx.x * 1024 + tid * 4;
    int d[4];
    int tot = 0;
#pragma unroll
    for (int j = 0; j < 4; ++j) {
        int i = base + j;
        d[j] = (i < NN) ? degi[i] : 0;
        tot += d[j];
    }
    s[tid] = tot;
    __syncthreads();
    // inclusive Hillis-Steele scan over thread totals
    for (int off = 1; off < 256; off <<= 1) {
        int v = (tid >= off) ? s[tid - off] : 0;
        __syncthreads();
        s[tid] += v;
        __syncthreads();
    }
    int run = part[blockIdx.x] + s[tid] - tot;  // exclusive prefix for this thread
#pragma unroll
    for (int j = 0; j < 4; ++j) {
        int i = base + j;
        if (i < NN) {
            rp[i] = run;
            if (i == NN - 1) rp[NN] = run + d[j];
            run += d[j];
        }
    }
}

__global__ __launch_bounds__(256) void make_dinv(const int* __restrict__ degi,
                                                 float* __restrict__ dinv) {
    int v = blockIdx.x * 256 + threadIdx.x;
    if (v < NN) dinv[v] = rsqrtf((float)(degi[v] + 1));  // +1 self-loop
}

__global__ __launch_bounds__(256) void scatter_csr(const int* __restrict__ src,
                                                   const int* __restrict__ dst,
                                                   const int* __restrict__ rp,
                                                   int* __restrict__ ctr,
                                                   const float* __restrict__ dinv,
                                                   uint2* __restrict__ csr) {
    int e = blockIdx.x * 256 + threadIdx.x;
    if (e >= NE) return;
    int s = src[e], d = dst[e];
    if (s < 0 || s >= NN || d < 0 || d >= NN) return;  // defensive: never OOB
    int pos = rp[d] + atomicAdd(&ctr[d], 1);
    if (pos < 0 || pos >= NE) return;
    uint2 v;
    v.x = (unsigned)s;
    v.y = __float_as_uint(dinv[s] * dinv[d]);
    csr[pos] = v;
}

// ---------------------------------------------------------------- GEMM 128x128
// C[M,128] (fp16) = A[M,128] (fp32) @ W[128,128] (fp32). W staged in LDS.
// 256 threads: (ty,tx) = 16x16; each thread: 4 rows x 8 cols.
__global__ __launch_bounds__(256) void gemm128(const float* __restrict__ A,
                                               const float* __restrict__ W,
                                               __half* __restrict__ C, int M) {
    __shared__ float Ws[FDIM * FDIM];
    {
        const float4* W4 = (const float4*)W;
        float4* S4 = (float4*)Ws;
        for (int i = threadIdx.x; i < FDIM * FDIM / 4; i += 256) S4[i] = W4[i];
    }
    __syncthreads();
    const int ty = threadIdx.x >> 4;
    const int tx = threadIdx.x & 15;
    const int row0 = blockIdx.x * 64 + ty * 4;
    int r[4];
#pragma unroll
    for (int i = 0; i < 4; ++i) r[i] = min(row0 + i, M - 1);

    float acc[4][8];
#pragma unroll
    for (int i = 0; i < 4; ++i)
#pragma unroll
        for (int j = 0; j < 8; ++j) acc[i][j] = 0.f;

    const float4* A4 = (const float4*)A;
    for (int k = 0; k < FDIM; k += 4) {
        float4 xv[4];
#pragma unroll
        for (int i = 0; i < 4; ++i) xv[i] = A4[r[i] * 32 + (k >> 2)];
#pragma unroll
        for (int kk = 0; kk < 4; ++kk) {
            const float4 wa = *(const float4*)(Ws + (k + kk) * FDIM + tx * 8);
            const float4 wb = *(const float4*)(Ws + (k + kk) * FDIM + tx * 8 + 4);
#pragma unroll
            for (int i = 0; i < 4; ++i) {
                const float xs = ((const float*)&xv[i])[kk];
                acc[i][0] = fmaf(xs, wa.x, acc[i][0]);
                acc[i][1] = fmaf(xs, wa.y, acc[i][1]);
                acc[i][2] = fmaf(xs, wa.z, acc[i][2]);
                acc[i][3] = fmaf(xs, wa.w, acc[i][3]);
                acc[i][4] = fmaf(xs, wb.x, acc[i][4]);
                acc[i][5] = fmaf(xs, wb.y, acc[i][5]);
                acc[i][6] = fmaf(xs, wb.z, acc[i][6]);
                acc[i][7] = fmaf(xs, wb.w, acc[i][7]);
            }
        }
    }
#pragma unroll
    for (int i = 0; i < 4; ++i) {
        int row = row0 + i;
        if (row < M) {
            __half2 h0 = __floats2half2_rn(acc[i][0], acc[i][1]);
            __half2 h1 = __floats2half2_rn(acc[i][2], acc[i][3]);
            __half2 h2 = __floats2half2_rn(acc[i][4], acc[i][5]);
            __half2 h3 = __floats2half2_rn(acc[i][6], acc[i][7]);
            uint4 pack;
            pack.x = *(unsigned*)&h0;
            pack.y = *(unsigned*)&h1;
            pack.z = *(unsigned*)&h2;
            pack.w = *(unsigned*)&h3;
            *(uint4*)(C + (size_t)row * FDIM + tx * 8) = pack;
        }
    }
}

// ---------------------------------------------------------------- aggregation
// out[v] = relu( dinv[v]^2 * h[v] + sum_{e: dst=v} w_e * h[src_e] + b )
// h is fp16: 32 lanes/node, 8 B (4 halves)/lane -> 256 B/row gather, fp32 acc.
// Edge loop unrolled x4 with independent gathers: 4 loads in flight per
// 32-lane group (was 1 -> latency-bound at 104 us, 30% HBM peak).
__device__ inline float4 h16x4_to_f4(uint2 u) {
    __half2 a = *(__half2*)&u.x;
    __half2 b = *(__half2*)&u.y;
    float2 fa = __half22float2(a);
    float2 fb = __half22float2(b);
    return make_float4(fa.x, fa.y, fb.x, fb.y);
}

__global__ __launch_bounds__(256) void gcn_agg(const __half* __restrict__ h,
                                               const uint2* __restrict__ csr,
                                               const int* __restrict__ rp,
                                               const float* __restrict__ dinv,
                                               const float* __restrict__ bias,
                                               float* __restrict__ out) {
    const int node = blockIdx.x * 8 + (threadIdx.x >> 5);
    const int fg = threadIdx.x & 31;
    const uint2* __restrict__ h8 = (const uint2*)h;  // 4 halves per uint2

    const float di = dinv[node];
    const float sw = di * di;
    float4 a = h16x4_to_f4(h8[node * 32 + fg]);
    float4 acc;
    acc.x = a.x * sw;
    acc.y = a.y * sw;
    acc.z = a.z * sw;
    acc.w = a.w * sw;

    int e0 = rp[node], e1 = rp[node + 1];
    if (e0 < 0) e0 = 0;
    if (e1 > NE) e1 = NE;

    int e = e0;
    for (; e + 4 <= e1; e += 4) {
        // 4 independent CSR loads (contiguous, L2-friendly), then 4
        // independent row-gathers -> 4 VMEM ops in flight.
        const uint2 c0 = csr[e + 0];
        const uint2 c1 = csr[e + 1];
        const uint2 c2 = csr[e + 2];
        const uint2 c3 = csr[e + 3];
        const int s0 = min((int)(c0.x & 0x7fffffffu), NN - 1);
        const int s1 = min((int)(c1.x & 0x7fffffffu), NN - 1);
        const int s2 = min((int)(c2.x & 0x7fffffffu), NN - 1);
        const int s3 = min((int)(c3.x & 0x7fffffffu), NN - 1);
        const uint2 v0 = h8[s0 * 32 + fg];
        const uint2 v1 = h8[s1 * 32 + fg];
        const uint2 v2 = h8[s2 * 32 + fg];
        const uint2 v3 = h8[s3 * 32 + fg];
        const float w0 = __uint_as_float(c0.y);
        const float w1 = __uint_as_float(c1.y);
        const float w2 = __uint_as_float(c2.y);
        const float w3 = __uint_as_float(c3.y);
        const float4 f0 = h16x4_to_f4(v0);
        const float4 f1 = h16x4_to_f4(v1);
        const float4 f2 = h16x4_to_f4(v2);
        const float4 f3 = h16x4_to_f4(v3);
        acc.x = fmaf(w0, f0.x, acc.x); acc.y = fmaf(w0, f0.y, acc.y);
        acc.z = fmaf(w0, f0.z, acc.z); acc.w = fmaf(w0, f0.w, acc.w);
        acc.x = fmaf(w1, f1.x, acc.x); acc.y = fmaf(w1, f1.y, acc.y);
        acc.z = fmaf(w1, f1.z, acc.z); acc.w = fmaf(w1, f1.w, acc.w);
        acc.x = fmaf(w2, f2.x, acc.x); acc.y = fmaf(w2, f2.y, acc.y);
        acc.z = fmaf(w2, f2.z, acc.z); acc.w = fmaf(w2, f2.w, acc.w);
        acc.x = fmaf(w3, f3.x, acc.x); acc.y = fmaf(w3, f3.y, acc.y);
        acc.z = fmaf(w3, f3.z, acc.z); acc.w = fmaf(w3, f3.w, acc.w);
    }
    for (; e < e1; ++e) {
        const uint2 srw = csr[e];
        const float w = __uint_as_float(srw.y);
        const int s = min((int)(srw.x & 0x7fffffffu), NN - 1);
        const float4 hv = h16x4_to_f4(h8[s * 32 + fg]);
        acc.x = fmaf(w, hv.x, acc.x);
        acc.y = fmaf(w, hv.y, acc.y);
        acc.z = fmaf(w, hv.z, acc.z);
        acc.w = fmaf(w, hv.w, acc.w);
    }
    const float4 b = ((const float4*)bias)[fg];
    float4 o;
    o.x = fmaxf(acc.x + b.x, 0.f);
    o.y = fmaxf(acc.y + b.y, 0.f);
    o.z = fmaxf(acc.z + b.z, 0.f);
    o.w = fmaxf(acc.w + b.w, 0.f);
    ((float4*)out)[node * 32 + fg] = o;
}

// ---------------------------------------------------------------- head + pool
// One block per graph. batch is sorted -> binary search node range, then
// per-thread dot(h[v], Wl)+tanh accumulated in registers, LDS tree-reduce,
// direct store. ZERO global atomics.
__global__ __launch_bounds__(256) void head_pool(const float* __restrict__ h,
                                                 const float* __restrict__ Wl,
                                                 const float* __restrict__ bl,
                                                 const int* __restrict__ batch,
                                                 float* __restrict__ out) {
    const int g = blockIdx.x;
    const int tid = threadIdx.x;

    int lo = 0, hi = NN;
    while (lo < hi) {
        int mid = (lo + hi) >> 1;
        if (batch[mid] < g) lo = mid + 1; else hi = mid;
    }
    const int start = lo;
    hi = NN;
    while (lo < hi) {
        int mid = (lo + hi) >> 1;
        if (batch[mid] <= g) lo = mid + 1; else hi = mid;
    }
    const int end = lo;

    __shared__ float Ws[FDIM * NACT];  // 4 KB
    for (int i = tid; i < FDIM * NACT; i += 256) Ws[i] = Wl[i];
    __syncthreads();

    float acc[NACT];
#pragma unroll
    for (int f = 0; f < NACT; ++f) acc[f] = 0.f;

    for (int v = start + tid; v < end; v += 256) {
        float o[NACT];
#pragma unroll
        for (int f = 0; f < NACT; ++f) o[f] = bl[f];
        const float4* h4 = (const float4*)h + (size_t)v * 32;
        for (int k4 = 0; k4 < 32; ++k4) {
            const float4 xv = h4[k4];
#pragma unroll
            for (int f = 0; f < NACT; ++f) {
                o[f] = fmaf(xv.x, Ws[(k4 * 4 + 0) * NACT + f], o[f]);
                o[f] = fmaf(xv.y, Ws[(k4 * 4 + 1) * NACT + f], o[f]);
                o[f] = fmaf(xv.z, Ws[(k4 * 4 + 2) * NACT + f], o[f]);
                o[f] = fmaf(xv.w, Ws[(k4 * 4 + 3) * NACT + f], o[f]);
            }
        }
#pragma unroll
        for (int f = 0; f < NACT; ++f) acc[f] += tanhf(o[f]);
    }

    __shared__ float red[256 * NACT];  // 8 KB
#pragma unroll
    for (int f = 0; f < NACT; ++f) red[tid * NACT + f] = acc[f];
    __syncthreads();
    for (int off = 128; off > 0; off >>= 1) {
        if (tid < off) {
#pragma unroll
            for (int f = 0; f < NACT; ++f)
                red[tid * NACT + f] += red[(tid + off) * NACT + f];
        }
        __syncthreads();
    }
    if (tid < NACT) {
        const float inv = 1.0f / fmaxf((float)(end - start), 1.0f);
        out[g * NACT + tid] = red[tid] * inv;
    }
}

// ---------------------------------------------------------------- launch

extern "C" void kernel_launch(void* const* d_in, const int* in_sizes, int n_in,
                              void* d_out, int out_size, void* d_ws, size_t ws_size,
                              hipStream_t stream) {
    const float* x = (const float*)d_in[0];
    const int* ei = (const int*)d_in[1];
    const int* batch = (const int*)d_in[2];
    const float* W1 = (const float*)d_in[3];
    const float* b1 = (const float*)d_in[4];
    const float* W2 = (const float*)d_in[5];
    const float* b2 = (const float*)d_in[6];
    const float* W3 = (const float*)d_in[7];
    const float* b3 = (const float*)d_in[8];
    const float* Wl = (const float*)d_in[9];
    const float* bl = (const float*)d_in[10];

    const int* src = ei;
    const int* dst = ei + NE;

    char* p = (char*)d_ws;
    auto alloc = [&](size_t bytes) {
        void* r = (void*)p;
        p += (bytes + 255) & ~(size_t)255;
        return r;
    };
    __half* hbuf = (__half*)alloc((size_t)NN * FDIM * 2);  // 25.6 MB (fp16)
    float* abuf  = (float*)alloc((size_t)NN * FDIM * 4);   // 51.2 MB
    uint2* csr   = (uint2*)alloc((size_t)NE * 8);          // 12.8 MB
    int* degi    = (int*)alloc(NN * 4);
    int* rp      = (int*)alloc((NN + 1) * 4);
    int* ctr     = (int*)alloc(NN * 4);
    float* dinv  = (float*)alloc(NN * 4);
    int* part    = (int*)alloc(4096);

    hipMemsetAsync(degi, 0, NN * 4, stream);
    hipMemsetAsync(ctr, 0, NN * 4, stream);

    const int NB_SCAN = (NN + 1023) / 1024;  // 98
    count_deg<<<(NE + 255) / 256, 256, 0, stream>>>(dst, degi);
    scan_bsum<<<NB_SCAN, 256, 0, stream>>>(degi, part);
    scan_part<<<1, 64, 0, stream>>>(part, NB_SCAN);
    scan_write<<<NB_SCAN, 256, 0, stream>>>(degi, part, rp);
    make_dinv<<<(NN + 255) / 256, 256, 0, stream>>>(degi, dinv);
    scatter_csr<<<(NE + 255) / 256, 256, 0, stream>>>(src, dst, rp, ctr, dinv, csr);

    gemm128<<<(NN + 63) / 64, 256, 0, stream>>>(x, W1, hbuf, NN);
    gcn_agg<<<NN / 8, 256, 0, stream>>>(hbuf, csr, rp, dinv, b1, abuf);
    gemm128<<<(NN + 63) / 64, 256, 0, stream>>>(abuf, W2, hbuf, NN);
    gcn_agg<<<NN / 8, 256, 0, stream>>>(hbuf, csr, rp, dinv, b2, abuf);
    gemm128<<<(NN + 63) / 64, 256, 0, stream>>>(abuf, W3, hbuf, NN);
    gcn_agg<<<NN / 8, 256, 0, stream>>>(hbuf, csr, rp, dinv, b3, abuf);

    head_pool<<<NG, 256, 0, stream>>>(abuf, Wl, bl, batch, (float*)d_out);
}

// Round 8
// 617.561 us; speedup vs baseline: 1.5607x; 1.0579x over previous
//
#include <hip/hip_runtime.h>
#include <hip/hip_fp16.h>

#define NN 100000
#define NE 1600000
#define FDIM 128
#define NACT 8
#define NG 1024

typedef __attribute__((ext_vector_type(8))) _Float16 half8;
typedef __attribute__((ext_vector_type(4))) float floatx4;

// ---------------------------------------------------------------- CSR build

__global__ __launch_bounds__(256) void count_deg(const int* __restrict__ dst,
                                                 int* __restrict__ degi) {
    int e = blockIdx.x * 256 + threadIdx.x;
    if (e < NE) {
        int d = dst[e];
        if (d >= 0 && d < NN) atomicAdd(&degi[d], 1);
    }
}

__global__ __launch_bounds__(256) void scan_bsum(const int* __restrict__ degi,
                                                 int* __restrict__ part) {
    __shared__ int s[256];
    int base = blockIdx.x * 1024 + threadIdx.x * 4;
    int tot = 0;
#pragma unroll
    for (int j = 0; j < 4; ++j) {
        int i = base + j;
        tot += (i < NN) ? degi[i] : 0;
    }
    s[threadIdx.x] = tot;
    __syncthreads();
    for (int off = 128; off > 0; off >>= 1) {
        if (threadIdx.x < off) s[threadIdx.x] += s[threadIdx.x + off];
        __syncthreads();
    }
    if (threadIdx.x == 0) part[blockIdx.x] = s[0];
}

__global__ void scan_part(int* __restrict__ part, int nb) {
    if (blockIdx.x == 0 && threadIdx.x == 0) {
        int run = 0;
        for (int i = 0; i < nb; ++i) {
            int v = part[i];
            part[i] = run;
            run += v;
        }
    }
}

__global__ __launch_bounds__(256) void scan_write(const int* __restrict__ degi,
                                                  const int* __restrict__ part,
                                                  int* __restrict__ rp) {
    __shared__ int s[256];
    const int tid = threadIdx.x;
    int base = blockIdx.x * 1024 + tid * 4;
    int d[4];
    int tot = 0;
#pragma unroll
    for (int j = 0; j < 4; ++j) {
        int i = base + j;
        d[j] = (i < NN) ? degi[i] : 0;
        tot += d[j];
    }
    s[tid] = tot;
    __syncthreads();
    for (int off = 1; off < 256; off <<= 1) {
        int v = (tid >= off) ? s[tid - off] : 0;
        __syncthreads();
        s[tid] += v;
        __syncthreads();
    }
    int run = part[blockIdx.x] + s[tid] - tot;
#pragma unroll
    for (int j = 0; j < 4; ++j) {
        int i = base + j;
        if (i < NN) {
            rp[i] = run;
            if (i == NN - 1) rp[NN] = run + d[j];
            run += d[j];
        }
    }
}

__global__ __launch_bounds__(256) void make_dinv(const int* __restrict__ degi,
                                                 float* __restrict__ dinv) {
    int v = blockIdx.x * 256 + threadIdx.x;
    if (v < NN) dinv[v] = rsqrtf((float)(degi[v] + 1));  // +1 self-loop
}

// 4B payload (src only): halves scatter footprint (12.8->6.4 MB) so XCD-L2
// write-combining works; weight recomputed in gcn_agg from dinv (identical
// product, no accuracy change).
__global__ __launch_bounds__(256) void scatter_csr(const int* __restrict__ src,
                                                   const int* __restrict__ dst,
                                                   const int* __restrict__ rp,
                                                   int* __restrict__ ctr,
                                                   int* __restrict__ csr) {
    int e = blockIdx.x * 256 + threadIdx.x;
    if (e >= NE) return;
    int s = src[e], d = dst[e];
    if (s < 0 || s >= NN || d < 0 || d >= NN) return;  // defensive: never OOB
    int pos = rp[d] + atomicAdd(&ctr[d], 1);
    if (pos < 0 || pos >= NE) return;
    csr[pos] = s;
}

// ---------------------------------------------------------------- W -> Wt fp16
// wt[m][c][k] = W_m[k][c], fp16. 3 matrices, 48 KB total.
__global__ __launch_bounds__(256) void prep_wt(const float* __restrict__ W1,
                                               const float* __restrict__ W2,
                                               const float* __restrict__ W3,
                                               __half* __restrict__ wt) {
    int i = blockIdx.x * 256 + threadIdx.x;
    if (i >= 3 * FDIM * FDIM) return;
    int m = i >> 14;
    int c = (i >> 7) & 127;
    int k = i & 127;
    const float* W = (m == 0) ? W1 : (m == 1) ? W2 : W3;
    wt[(m << 14) + (c << 7) + k] = __float2half(W[(k << 7) + c]);
}

// ---------------------------------------------------------------- GEMM (MFMA)
// C[M,128] (fp16) = A[M,128] (fp32, cvt to fp16 in-reg) @ W (fp16, wt[c][k]).
// 4 waves/block, each wave: 16 rows x 128 cols via mfma_f32_16x16x32_f16.
// Fragment layouts (m89/m91-verified family):
//   A: lane holds A[row0 + (l&15)][kb*32 + (l>>4)*8 + j]
//   B: lane holds W[kb*32 + (l>>4)*8 + j][ct*16 + (l&15)]  (= wt[c][k] contig)
//   D: col = l&15, row = (l>>4)*4 + reg
// C staged through padded LDS (pitch 136 halves -> <=2-way banks) for
// coalesced uint4 global stores.
__global__ __launch_bounds__(256) void gemm_mfma(const float* __restrict__ A,
                                                 const __half* __restrict__ wt,
                                                 __half* __restrict__ C, int M) {
    __shared__ __half Cs[64 * 136];  // 17 KB
    const int tid = threadIdx.x;
    const int wid = tid >> 6;
    const int lane = tid & 63;
    const int l15 = lane & 15;
    const int lk = lane >> 4;  // 0..3
    const int row0 = blockIdx.x * 64 + wid * 16;

    const int arow = min(row0 + l15, M - 1);
    const float* Ar = A + (size_t)arow * FDIM;

    half8 afr[4];
#pragma unroll
    for (int kb = 0; kb < 4; ++kb) {
        const float4 f0 = *(const float4*)(Ar + kb * 32 + lk * 8);
        const float4 f1 = *(const float4*)(Ar + kb * 32 + lk * 8 + 4);
        half8 h;
        h[0] = (_Float16)f0.x; h[1] = (_Float16)f0.y;
        h[2] = (_Float16)f0.z; h[3] = (_Float16)f0.w;
        h[4] = (_Float16)f1.x; h[5] = (_Float16)f1.y;
        h[6] = (_Float16)f1.z; h[7] = (_Float16)f1.w;
        afr[kb] = h;
    }

    floatx4 acc[8];
#pragma unroll
    for (int ct = 0; ct < 8; ++ct) acc[ct] = (floatx4){0.f, 0.f, 0.f, 0.f};

#pragma unroll
    for (int ct = 0; ct < 8; ++ct) {
#pragma unroll
        for (int kb = 0; kb < 4; ++kb) {
            const half8 b = *(const half8*)(wt + (ct * 16 + l15) * FDIM + kb * 32 + lk * 8);
            acc[ct] = __builtin_amdgcn_mfma_f32_16x16x32_f16(afr[kb], b, acc[ct], 0, 0, 0);
        }
    }

    // stage to LDS: row_in_block = wid*16 + lk*4 + r, col = ct*16 + l15
#pragma unroll
    for (int ct = 0; ct < 8; ++ct) {
#pragma unroll
        for (int r = 0; r < 4; ++r) {
            Cs[(wid * 16 + lk * 4 + r) * 136 + ct * 16 + l15] = __float2half(acc[ct][r]);
        }
    }
    __syncthreads();

    // cooperative coalesced store: 64 rows x 16 uint4
#pragma unroll
    for (int j = 0; j < 4; ++j) {
        const int idx = tid + j * 256;       // 0..1023
        const int rb = idx >> 4;             // row in block
        const int cq = idx & 15;             // uint4 within row
        const int row = blockIdx.x * 64 + rb;
        if (row < M) {
            const uint4 v = *(const uint4*)(Cs + rb * 136 + cq * 8);
            *(uint4*)(C + (size_t)row * FDIM + cq * 8) = v;
        }
    }
}

// ---------------------------------------------------------------- aggregation
// out[v] = relu( dinv[v]^2 * h[v] + sum_{e: dst=v} dinv[s]*dinv[v] * h[s] + b )
// h fp16, fp32 accumulate; x4 unrolled (4 gathers in flight / 32-lane group).
__device__ inline float4 h16x4_to_f4(uint2 u) {
    __half2 a = *(__half2*)&u.x;
    __half2 b = *(__half2*)&u.y;
    float2 fa = __half22float2(a);
    float2 fb = __half22float2(b);
    return make_float4(fa.x, fa.y, fb.x, fb.y);
}

__global__ __launch_bounds__(256) void gcn_agg(const __half* __restrict__ h,
                                               const int* __restrict__ csr,
                                               const int* __restrict__ rp,
                                               const float* __restrict__ dinv,
                                               const float* __restrict__ bias,
                                               float* __restrict__ out) {
    const int node = blockIdx.x * 8 + (threadIdx.x >> 5);
    const int fg = threadIdx.x & 31;
    const uint2* __restrict__ h8 = (const uint2*)h;

    const float di = dinv[node];
    const float sw = di * di;
    float4 a = h16x4_to_f4(h8[node * 32 + fg]);
    float4 acc;
    acc.x = a.x * sw;
    acc.y = a.y * sw;
    acc.z = a.z * sw;
    acc.w = a.w * sw;

    int e0 = rp[node], e1 = rp[node + 1];
    if (e0 < 0) e0 = 0;
    if (e1 > NE) e1 = NE;

    int e = e0;
    for (; e + 4 <= e1; e += 4) {
        const int s0 = min((int)(((unsigned)csr[e + 0]) & 0x7fffffffu), NN - 1);
        const int s1 = min((int)(((unsigned)csr[e + 1]) & 0x7fffffffu), NN - 1);
        const int s2 = min((int)(((unsigned)csr[e + 2]) & 0x7fffffffu), NN - 1);
        const int s3 = min((int)(((unsigned)csr[e + 3]) & 0x7fffffffu), NN - 1);
        const uint2 v0 = h8[s0 * 32 + fg];
        const uint2 v1 = h8[s1 * 32 + fg];
        const uint2 v2 = h8[s2 * 32 + fg];
        const uint2 v3 = h8[s3 * 32 + fg];
        const float w0 = dinv[s0] * di;
        const float w1 = dinv[s1] * di;
        const float w2 = dinv[s2] * di;
        const float w3 = dinv[s3] * di;
        const float4 f0 = h16x4_to_f4(v0);
        const float4 f1 = h16x4_to_f4(v1);
        const float4 f2 = h16x4_to_f4(v2);
        const float4 f3 = h16x4_to_f4(v3);
        acc.x = fmaf(w0, f0.x, acc.x); acc.y = fmaf(w0, f0.y, acc.y);
        acc.z = fmaf(w0, f0.z, acc.z); acc.w = fmaf(w0, f0.w, acc.w);
        acc.x = fmaf(w1, f1.x, acc.x); acc.y = fmaf(w1, f1.y, acc.y);
        acc.z = fmaf(w1, f1.z, acc.z); acc.w = fmaf(w1, f1.w, acc.w);
        acc.x = fmaf(w2, f2.x, acc.x); acc.y = fmaf(w2, f2.y, acc.y);
        acc.z = fmaf(w2, f2.z, acc.z); acc.w = fmaf(w2, f2.w, acc.w);
        acc.x = fmaf(w3, f3.x, acc.x); acc.y = fmaf(w3, f3.y, acc.y);
        acc.z = fmaf(w3, f3.z, acc.z); acc.w = fmaf(w3, f3.w, acc.w);
    }
    for (; e < e1; ++e) {
        const int s = min((int)(((unsigned)csr[e]) & 0x7fffffffu), NN - 1);
        const float w = dinv[s] * di;
        const float4 hv = h16x4_to_f4(h8[s * 32 + fg]);
        acc.x = fmaf(w, hv.x, acc.x);
        acc.y = fmaf(w, hv.y, acc.y);
        acc.z = fmaf(w, hv.z, acc.z);
        acc.w = fmaf(w, hv.w, acc.w);
    }
    const float4 b = ((const float4*)bias)[fg];
    float4 o;
    o.x = fmaxf(acc.x + b.x, 0.f);
    o.y = fmaxf(acc.y + b.y, 0.f);
    o.z = fmaxf(acc.z + b.z, 0.f);
    o.w = fmaxf(acc.w + b.w, 0.f);
    ((float4*)out)[node * 32 + fg] = o;
}

// ---------------------------------------------------------------- head + pool
__global__ __launch_bounds__(256) void head_pool(const float* __restrict__ h,
                                                 const float* __restrict__ Wl,
                                                 const float* __restrict__ bl,
                                                 const int* __restrict__ batch,
                                                 float* __restrict__ out) {
    const int g = blockIdx.x;
    const int tid = threadIdx.x;

    int lo = 0, hi = NN;
    while (lo < hi) {
        int mid = (lo + hi) >> 1;
        if (batch[mid] < g) lo = mid + 1; else hi = mid;
    }
    const int start = lo;
    hi = NN;
    while (lo < hi) {
        int mid = (lo + hi) >> 1;
        if (batch[mid] <= g) lo = mid + 1; else hi = mid;
    }
    const int end = lo;

    __shared__ float Ws[FDIM * NACT];
    for (int i = tid; i < FDIM * NACT; i += 256) Ws[i] = Wl[i];
    __syncthreads();

    float acc[NACT];
#pragma unroll
    for (int f = 0; f < NACT; ++f) acc[f] = 0.f;

    for (int v = start + tid; v < end; v += 256) {
        float o[NACT];
#pragma unroll
        for (int f = 0; f < NACT; ++f) o[f] = bl[f];
        const float4* h4 = (const float4*)h + (size_t)v * 32;
        for (int k4 = 0; k4 < 32; ++k4) {
            const float4 xv = h4[k4];
#pragma unroll
            for (int f = 0; f < NACT; ++f) {
                o[f] = fmaf(xv.x, Ws[(k4 * 4 + 0) * NACT + f], o[f]);
                o[f] = fmaf(xv.y, Ws[(k4 * 4 + 1) * NACT + f], o[f]);
                o[f] = fmaf(xv.z, Ws[(k4 * 4 + 2) * NACT + f], o[f]);
                o[f] = fmaf(xv.w, Ws[(k4 * 4 + 3) * NACT + f], o[f]);
            }
        }
#pragma unroll
        for (int f = 0; f < NACT; ++f) acc[f] += tanhf(o[f]);
    }

    __shared__ float red[256 * NACT];
#pragma unroll
    for (int f = 0; f < NACT; ++f) red[tid * NACT + f] = acc[f];
    __syncthreads();
    for (int off = 128; off > 0; off >>= 1) {
        if (tid < off) {
#pragma unroll
            for (int f = 0; f < NACT; ++f)
                red[tid * NACT + f] += red[(tid + off) * NACT + f];
        }
        __syncthreads();
    }
    if (tid < NACT) {
        const float inv = 1.0f / fmaxf((float)(end - start), 1.0f);
        out[g * NACT + tid] = red[tid] * inv;
    }
}

// ---------------------------------------------------------------- launch

extern "C" void kernel_launch(void* const* d_in, const int* in_sizes, int n_in,
                              void* d_out, int out_size, void* d_ws, size_t ws_size,
                              hipStream_t stream) {
    const float* x = (const float*)d_in[0];
    const int* ei = (const int*)d_in[1];
    const int* batch = (const int*)d_in[2];
    const float* W1 = (const float*)d_in[3];
    const float* b1 = (const float*)d_in[4];
    const float* W2 = (const float*)d_in[5];
    const float* b2 = (const float*)d_in[6];
    const float* W3 = (const float*)d_in[7];
    const float* b3 = (const float*)d_in[8];
    const float* Wl = (const float*)d_in[9];
    const float* bl = (const float*)d_in[10];

    const int* src = ei;
    const int* dst = ei + NE;

    char* p = (char*)d_ws;
    auto alloc = [&](size_t bytes) {
        void* r = (void*)p;
        p += (bytes + 255) & ~(size_t)255;
        return r;
    };
    __half* hbuf = (__half*)alloc((size_t)NN * FDIM * 2);  // 25.6 MB (fp16)
    float* abuf  = (float*)alloc((size_t)NN * FDIM * 4);   // 51.2 MB
    int* csr     = (int*)alloc((size_t)NE * 4);            // 6.4 MB
    __half* wt   = (__half*)alloc(3 * FDIM * FDIM * 2);    // 96 KB
    int* degi    = (int*)alloc(NN * 4);
    int* rp      = (int*)alloc((NN + 1) * 4);
    int* ctr     = (int*)alloc(NN * 4);
    float* dinv  = (float*)alloc(NN * 4);
    int* part    = (int*)alloc(4096);

    hipMemsetAsync(degi, 0, NN * 4, stream);
    hipMemsetAsync(ctr, 0, NN * 4, stream);

    const int NB_SCAN = (NN + 1023) / 1024;  // 98
    prep_wt<<<(3 * FDIM * FDIM + 255) / 256, 256, 0, stream>>>(W1, W2, W3, wt);
    count_deg<<<(NE + 255) / 256, 256, 0, stream>>>(dst, degi);
    scan_bsum<<<NB_SCAN, 256, 0, stream>>>(degi, part);
    scan_part<<<1, 64, 0, stream>>>(part, NB_SCAN);
    scan_write<<<NB_SCAN, 256, 0, stream>>>(degi, part, rp);
    make_dinv<<<(NN + 255) / 256, 256, 0, stream>>>(degi, dinv);
    scatter_csr<<<(NE + 255) / 256, 256, 0, stream>>>(src, dst, rp, ctr, csr);

    const int GB = (NN + 63) / 64;  // 1563
    gemm_mfma<<<GB, 256, 0, stream>>>(x, wt, hbuf, NN);
    gcn_agg<<<NN / 8, 256, 0, stream>>>(hbuf, csr, rp, dinv, b1, abuf);
    gemm_mfma<<<GB, 256, 0, stream>>>(abuf, wt + FDIM * FDIM, hbuf, NN);
    gcn_agg<<<NN / 8, 256, 0, stream>>>(hbuf, csr, rp, dinv, b2, abuf);
    gemm_mfma<<<GB, 256, 0, stream>>>(abuf, wt + 2 * FDIM * FDIM, hbuf, NN);
    gcn_agg<<<NN / 8, 256, 0, stream>>>(hbuf, csr, rp, dinv, b3, abuf);

    head_pool<<<NG, 256, 0, stream>>>(abuf, Wl, bl, batch, (float*)d_out);
}

// Round 9
// 588.948 us; speedup vs baseline: 1.6365x; 1.0486x over previous
//
#include <hip/hip_runtime.h>
#include <hip/hip_fp16.h>

#define NN 100000
#define NE 1600000
#define FDIM 128
#define NACT 8
#define NG 1024

typedef __attribute__((ext_vector_type(8))) _Float16 half8;
typedef __attribute__((ext_vector_type(4))) float floatx4;

// ---------------------------------------------------------------- CSR build

// x4 strided unroll: 4 independent (non-returning) atomics in flight/lane.
__global__ __launch_bounds__(256) void count_deg(const int* __restrict__ dst,
                                                 int* __restrict__ degi) {
    const int base = blockIdx.x * 1024 + threadIdx.x;
#pragma unroll
    for (int j = 0; j < 4; ++j) {
        int e = base + j * 256;
        if (e < NE) {
            int d = dst[e];
            if (d >= 0 && d < NN) atomicAdd(&degi[d], 1);
        }
    }
}

__global__ __launch_bounds__(256) void scan_bsum(const int* __restrict__ degi,
                                                 int* __restrict__ part) {
    __shared__ int s[256];
    int base = blockIdx.x * 1024 + threadIdx.x * 4;
    int tot = 0;
#pragma unroll
    for (int j = 0; j < 4; ++j) {
        int i = base + j;
        tot += (i < NN) ? degi[i] : 0;
    }
    s[threadIdx.x] = tot;
    __syncthreads();
    for (int off = 128; off > 0; off >>= 1) {
        if (threadIdx.x < off) s[threadIdx.x] += s[threadIdx.x + off];
        __syncthreads();
    }
    if (threadIdx.x == 0) part[blockIdx.x] = s[0];
}

__global__ void scan_part(int* __restrict__ part, int nb) {
    if (blockIdx.x == 0 && threadIdx.x == 0) {
        int run = 0;
        for (int i = 0; i < nb; ++i) {
            int v = part[i];
            part[i] = run;
            run += v;
        }
    }
}

__global__ __launch_bounds__(256) void scan_write(const int* __restrict__ degi,
                                                  const int* __restrict__ part,
                                                  int* __restrict__ rp) {
    __shared__ int s[256];
    const int tid = threadIdx.x;
    int base = blockIdx.x * 1024 + tid * 4;
    int d[4];
    int tot = 0;
#pragma unroll
    for (int j = 0; j < 4; ++j) {
        int i = base + j;
        d[j] = (i < NN) ? degi[i] : 0;
        tot += d[j];
    }
    s[tid] = tot;
    __syncthreads();
    for (int off = 1; off < 256; off <<= 1) {
        int v = (tid >= off) ? s[tid - off] : 0;
        __syncthreads();
        s[tid] += v;
        __syncthreads();
    }
    int run = part[blockIdx.x] + s[tid] - tot;
#pragma unroll
    for (int j = 0; j < 4; ++j) {
        int i = base + j;
        if (i < NN) {
            rp[i] = run;
            if (i == NN - 1) rp[NN] = run + d[j];
            run += d[j];
        }
    }
}

__global__ __launch_bounds__(256) void make_dinv(const int* __restrict__ degi,
                                                 float* __restrict__ dinv) {
    int v = blockIdx.x * 256 + threadIdx.x;
    if (v < NN) dinv[v] = rsqrtf((float)(degi[v] + 1));  // +1 self-loop
}

// x4 strided unroll: the per-lane chain rp-load -> returning atomicAdd ->
// scattered store was latency-bound (R8: 100 us, VALU 0.6%, 1.2 TB/s).
// 4 independent chains in flight. WRITE_SIZE stays ~107 MB (64B-line floor).
__global__ __launch_bounds__(256) void scatter_csr(const int* __restrict__ src,
                                                   const int* __restrict__ dst,
                                                   const int* __restrict__ rp,
                                                   int* __restrict__ ctr,
                                                   int* __restrict__ csr) {
    const int base = blockIdx.x * 1024 + threadIdx.x;
    int s[4], d[4];
    bool ok[4];
#pragma unroll
    for (int j = 0; j < 4; ++j) {
        int e = base + j * 256;
        bool in = e < NE;
        s[j] = in ? src[e] : 0;
        d[j] = in ? dst[e] : 0;
        ok[j] = in && s[j] >= 0 && s[j] < NN && d[j] >= 0 && d[j] < NN;
    }
    int pos[4];
#pragma unroll
    for (int j = 0; j < 4; ++j)
        pos[j] = ok[j] ? (rp[d[j]] + atomicAdd(&ctr[d[j]], 1)) : -1;
#pragma unroll
    for (int j = 0; j < 4; ++j)
        if (pos[j] >= 0 && pos[j] < NE) csr[pos[j]] = s[j];
}

// ---------------------------------------------------------------- W -> Wt fp16
// wt[m][c][k] = W_m[k][c], fp16. 3 matrices, 96 KB total.
__global__ __launch_bounds__(256) void prep_wt(const float* __restrict__ W1,
                                               const float* __restrict__ W2,
                                               const float* __restrict__ W3,
                                               __half* __restrict__ wt) {
    int i = blockIdx.x * 256 + threadIdx.x;
    if (i >= 3 * FDIM * FDIM) return;
    int m = i >> 14;
    int c = (i >> 7) & 127;
    int k = i & 127;
    const float* W = (m == 0) ? W1 : (m == 1) ? W2 : W3;
    wt[(m << 14) + (c << 7) + k] = __float2half(W[(k << 7) + c]);
}

// ---------------------------------------------------------------- GEMM (MFMA)
// C[M,128] (fp16) = A[M,128] (fp32, cvt to fp16 in-reg) @ W (fp16, wt[c][k]).
// 4 waves/block, each wave: 16 rows x 128 cols via mfma_f32_16x16x32_f16.
__global__ __launch_bounds__(256) void gemm_mfma(const float* __restrict__ A,
                                                 const __half* __restrict__ wt,
                                                 __half* __restrict__ C, int M) {
    __shared__ __half Cs[64 * 136];  // 17 KB
    const int tid = threadIdx.x;
    const int wid = tid >> 6;
    const int lane = tid & 63;
    const int l15 = lane & 15;
    const int lk = lane >> 4;  // 0..3
    const int row0 = blockIdx.x * 64 + wid * 16;

    const int arow = min(row0 + l15, M - 1);
    const float* Ar = A + (size_t)arow * FDIM;

    half8 afr[4];
#pragma unroll
    for (int kb = 0; kb < 4; ++kb) {
        const float4 f0 = *(const float4*)(Ar + kb * 32 + lk * 8);
        const float4 f1 = *(const float4*)(Ar + kb * 32 + lk * 8 + 4);
        half8 h;
        h[0] = (_Float16)f0.x; h[1] = (_Float16)f0.y;
        h[2] = (_Float16)f0.z; h[3] = (_Float16)f0.w;
        h[4] = (_Float16)f1.x; h[5] = (_Float16)f1.y;
        h[6] = (_Float16)f1.z; h[7] = (_Float16)f1.w;
        afr[kb] = h;
    }

    floatx4 acc[8];
#pragma unroll
    for (int ct = 0; ct < 8; ++ct) acc[ct] = (floatx4){0.f, 0.f, 0.f, 0.f};

#pragma unroll
    for (int ct = 0; ct < 8; ++ct) {
#pragma unroll
        for (int kb = 0; kb < 4; ++kb) {
            const half8 b = *(const half8*)(wt + (ct * 16 + l15) * FDIM + kb * 32 + lk * 8);
            acc[ct] = __builtin_amdgcn_mfma_f32_16x16x32_f16(afr[kb], b, acc[ct], 0, 0, 0);
        }
    }

    // stage to LDS: row_in_block = wid*16 + lk*4 + r, col = ct*16 + l15
#pragma unroll
    for (int ct = 0; ct < 8; ++ct) {
#pragma unroll
        for (int r = 0; r < 4; ++r) {
            Cs[(wid * 16 + lk * 4 + r) * 136 + ct * 16 + l15] = __float2half(acc[ct][r]);
        }
    }
    __syncthreads();

    // cooperative coalesced store: 64 rows x 16 uint4
#pragma unroll
    for (int j = 0; j < 4; ++j) {
        const int idx = tid + j * 256;       // 0..1023
        const int rb = idx >> 4;             // row in block
        const int cq = idx & 15;             // uint4 within row
        const int row = blockIdx.x * 64 + rb;
        if (row < M) {
            const uint4 v = *(const uint4*)(Cs + rb * 136 + cq * 8);
            *(uint4*)(C + (size_t)row * FDIM + cq * 8) = v;
        }
    }
}

// ---------------------------------------------------------------- aggregation
// out[v] = relu( dinv[v]^2 * h[v] + sum_{e: dst=v} dinv[s]*dinv[v] * h[s] + b )
// h fp16, fp32 accumulate; x4 unrolled (4 gathers in flight / 32-lane group).
__device__ inline float4 h16x4_to_f4(uint2 u) {
    __half2 a = *(__half2*)&u.x;
    __half2 b = *(__half2*)&u.y;
    float2 fa = __half22float2(a);
    float2 fb = __half22float2(b);
    return make_float4(fa.x, fa.y, fb.x, fb.y);
}

__global__ __launch_bounds__(256) void gcn_agg(const __half* __restrict__ h,
                                               const int* __restrict__ csr,
                                               const int* __restrict__ rp,
                                               const float* __restrict__ dinv,
                                               const float* __restrict__ bias,
                                               float* __restrict__ out) {
    const int node = blockIdx.x * 8 + (threadIdx.x >> 5);
    const int fg = threadIdx.x & 31;
    const uint2* __restrict__ h8 = (const uint2*)h;

    const float di = dinv[node];
    const float sw = di * di;
    float4 a = h16x4_to_f4(h8[node * 32 + fg]);
    float4 acc;
    acc.x = a.x * sw;
    acc.y = a.y * sw;
    acc.z = a.z * sw;
    acc.w = a.w * sw;

    int e0 = rp[node], e1 = rp[node + 1];
    if (e0 < 0) e0 = 0;
    if (e1 > NE) e1 = NE;

    int e = e0;
    for (; e + 4 <= e1; e += 4) {
        const int s0 = min((int)(((unsigned)csr[e + 0]) & 0x7fffffffu), NN - 1);
        const int s1 = min((int)(((unsigned)csr[e + 1]) & 0x7fffffffu), NN - 1);
        const int s2 = min((int)(((unsigned)csr[e + 2]) & 0x7fffffffu), NN - 1);
        const int s3 = min((int)(((unsigned)csr[e + 3]) & 0x7fffffffu), NN - 1);
        const uint2 v0 = h8[s0 * 32 + fg];
        const uint2 v1 = h8[s1 * 32 + fg];
        const uint2 v2 = h8[s2 * 32 + fg];
        const uint2 v3 = h8[s3 * 32 + fg];
        const float w0 = dinv[s0] * di;
        const float w1 = dinv[s1] * di;
        const float w2 = dinv[s2] * di;
        const float w3 = dinv[s3] * di;
        const float4 f0 = h16x4_to_f4(v0);
        const float4 f1 = h16x4_to_f4(v1);
        const float4 f2 = h16x4_to_f4(v2);
        const float4 f3 = h16x4_to_f4(v3);
        acc.x = fmaf(w0, f0.x, acc.x); acc.y = fmaf(w0, f0.y, acc.y);
        acc.z = fmaf(w0, f0.z, acc.z); acc.w = fmaf(w0, f0.w, acc.w);
        acc.x = fmaf(w1, f1.x, acc.x); acc.y = fmaf(w1, f1.y, acc.y);
        acc.z = fmaf(w1, f1.z, acc.z); acc.w = fmaf(w1, f1.w, acc.w);
        acc.x = fmaf(w2, f2.x, acc.x); acc.y = fmaf(w2, f2.y, acc.y);
        acc.z = fmaf(w2, f2.z, acc.z); acc.w = fmaf(w2, f2.w, acc.w);
        acc.x = fmaf(w3, f3.x, acc.x); acc.y = fmaf(w3, f3.y, acc.y);
        acc.z = fmaf(w3, f3.z, acc.z); acc.w = fmaf(w3, f3.w, acc.w);
    }
    for (; e < e1; ++e) {
        const int s = min((int)(((unsigned)csr[e]) & 0x7fffffffu), NN - 1);
        const float w = dinv[s] * di;
        const float4 hv = h16x4_to_f4(h8[s * 32 + fg]);
        acc.x = fmaf(w, hv.x, acc.x);
        acc.y = fmaf(w, hv.y, acc.y);
        acc.z = fmaf(w, hv.z, acc.z);
        acc.w = fmaf(w, hv.w, acc.w);
    }
    const float4 b = ((const float4*)bias)[fg];
    float4 o;
    o.x = fmaxf(acc.x + b.x, 0.f);
    o.y = fmaxf(acc.y + b.y, 0.f);
    o.z = fmaxf(acc.z + b.z, 0.f);
    o.w = fmaxf(acc.w + b.w, 0.f);
    ((float4*)out)[node * 32 + fg] = o;
}

// ---------------------------------------------------------------- head + pool
__global__ __launch_bounds__(256) void head_pool(const float* __restrict__ h,
                                                 const float* __restrict__ Wl,
                                                 const float* __restrict__ bl,
                                                 const int* __restrict__ batch,
                                                 float* __restrict__ out) {
    const int g = blockIdx.x;
    const int tid = threadIdx.x;

    int lo = 0, hi = NN;
    while (lo < hi) {
        int mid = (lo + hi) >> 1;
        if (batch[mid] < g) lo = mid + 1; else hi = mid;
    }
    const int start = lo;
    hi = NN;
    while (lo < hi) {
        int mid = (lo + hi) >> 1;
        if (batch[mid] <= g) lo = mid + 1; else hi = mid;
    }
    const int end = lo;

    __shared__ float Ws[FDIM * NACT];
    for (int i = tid; i < FDIM * NACT; i += 256) Ws[i] = Wl[i];
    __syncthreads();

    float acc[NACT];
#pragma unroll
    for (int f = 0; f < NACT; ++f) acc[f] = 0.f;

    for (int v = start + tid; v < end; v += 256) {
        float o[NACT];
#pragma unroll
        for (int f = 0; f < NACT; ++f) o[f] = bl[f];
        const float4* h4 = (const float4*)h + (size_t)v * 32;
        for (int k4 = 0; k4 < 32; ++k4) {
            const float4 xv = h4[k4];
#pragma unroll
            for (int f = 0; f < NACT; ++f) {
                o[f] = fmaf(xv.x, Ws[(k4 * 4 + 0) * NACT + f], o[f]);
                o[f] = fmaf(xv.y, Ws[(k4 * 4 + 1) * NACT + f], o[f]);
                o[f] = fmaf(xv.z, Ws[(k4 * 4 + 2) * NACT + f], o[f]);
                o[f] = fmaf(xv.w, Ws[(k4 * 4 + 3) * NACT + f], o[f]);
            }
        }
#pragma unroll
        for (int f = 0; f < NACT; ++f) acc[f] += tanhf(o[f]);
    }

    __shared__ float red[256 * NACT];
#pragma unroll
    for (int f = 0; f < NACT; ++f) red[tid * NACT + f] = acc[f];
    __syncthreads();
    for (int off = 128; off > 0; off >>= 1) {
        if (tid < off) {
#pragma unroll
            for (int f = 0; f < NACT; ++f)
                red[tid * NACT + f] += red[(tid + off) * NACT + f];
        }
        __syncthreads();
    }
    if (tid < NACT) {
        const float inv = 1.0f / fmaxf((float)(end - start), 1.0f);
        out[g * NACT + tid] = red[tid] * inv;
    }
}

// ---------------------------------------------------------------- launch

extern "C" void kernel_launch(void* const* d_in, const int* in_sizes, int n_in,
                              void* d_out, int out_size, void* d_ws, size_t ws_size,
                              hipStream_t stream) {
    const float* x = (const float*)d_in[0];
    const int* ei = (const int*)d_in[1];
    const int* batch = (const int*)d_in[2];
    const float* W1 = (const float*)d_in[3];
    const float* b1 = (const float*)d_in[4];
    const float* W2 = (const float*)d_in[5];
    const float* b2 = (const float*)d_in[6];
    const float* W3 = (const float*)d_in[7];
    const float* b3 = (const float*)d_in[8];
    const float* Wl = (const float*)d_in[9];
    const float* bl = (const float*)d_in[10];

    const int* src = ei;
    const int* dst = ei + NE;

    char* p = (char*)d_ws;
    auto alloc = [&](size_t bytes) {
        void* r = (void*)p;
        p += (bytes + 255) & ~(size_t)255;
        return r;
    };
    __half* hbuf = (__half*)alloc((size_t)NN * FDIM * 2);  // 25.6 MB (fp16)
    float* abuf  = (float*)alloc((size_t)NN * FDIM * 4);   // 51.2 MB
    int* csr     = (int*)alloc((size_t)NE * 4);            // 6.4 MB
    __half* wt   = (__half*)alloc(3 * FDIM * FDIM * 2);    // 96 KB
    int* degi    = (int*)alloc(NN * 4);
    int* rp      = (int*)alloc((NN + 1) * 4);
    int* ctr     = (int*)alloc(NN * 4);
    float* dinv  = (float*)alloc(NN * 4);
    int* part    = (int*)alloc(4096);

    hipMemsetAsync(degi, 0, NN * 4, stream);
    hipMemsetAsync(ctr, 0, NN * 4, stream);

    const int NB_SCAN = (NN + 1023) / 1024;  // 98
    const int NB_EDGE = (NE + 1023) / 1024;  // 1563
    prep_wt<<<(3 * FDIM * FDIM + 255) / 256, 256, 0, stream>>>(W1, W2, W3, wt);
    count_deg<<<NB_EDGE, 256, 0, stream>>>(dst, degi);
    scan_bsum<<<NB_SCAN, 256, 0, stream>>>(degi, part);
    scan_part<<<1, 64, 0, stream>>>(part, NB_SCAN);
    scan_write<<<NB_SCAN, 256, 0, stream>>>(degi, part, rp);
    make_dinv<<<(NN + 255) / 256, 256, 0, stream>>>(degi, dinv);
    scatter_csr<<<NB_EDGE, 256, 0, stream>>>(src, dst, rp, ctr, csr);

    const int GB = (NN + 63) / 64;  // 1563
    gemm_mfma<<<GB, 256, 0, stream>>>(x, wt, hbuf, NN);
    gcn_agg<<<NN / 8, 256, 0, stream>>>(hbuf, csr, rp, dinv, b1, abuf);
    gemm_mfma<<<GB, 256, 0, stream>>>(abuf, wt + FDIM * FDIM, hbuf, NN);
    gcn_agg<<<NN / 8, 256, 0, stream>>>(hbuf, csr, rp, dinv, b2, abuf);
    gemm_mfma<<<GB, 256, 0, stream>>>(abuf, wt + 2 * FDIM * FDIM, hbuf, NN);
    gcn_agg<<<NN / 8, 256, 0, stream>>>(hbuf, csr, rp, dinv, b3, abuf);

    head_pool<<<NG, 256, 0, stream>>>(abuf, Wl, bl, batch, (float*)d_out);
}